// Round 7
// baseline (324.959 us; speedup 1.0000x reference)
//
#include <hip/hip_runtime.h>

// Problem constants
#define BB 256      // batch
#define CCH 512     // channels
#define HW 196      // 14*14 spatial
#define TT 197      // templates_b rows (196 + 1 negative)
#define TROWS 208   // padded T rows (13 * 16)
#define TBK 224     // padded K for templates (7 * 32)
#define CST (CCH * TROWS)   // colp per-g stride

typedef __attribute__((ext_vector_type(8))) short bf16x8;
typedef __attribute__((ext_vector_type(4))) float f32x4;
typedef __attribute__((ext_vector_type(4))) unsigned short us4;

__device__ __forceinline__ unsigned short f2bf(float f) {
    union { float f; unsigned u; } v; v.f = f;
    unsigned r = v.u + 0x7FFFu + ((v.u >> 16) & 1u);   // round-to-nearest-even
    return (unsigned short)(r >> 16);
}
__device__ __forceinline__ float bf2f(unsigned short h) {
    union { unsigned u; float f; } v; v.u = ((unsigned)h) << 16;
    return v.f;
}

// ---- prep: wgs 0..181 convert templates_b*tau -> bf16 zero-padded 208x224;
// wg 182: gmax = max(templates_f) (center peak is in every 14x14 window, so
// max(sel) == max(templates_f)) + zero-padded pT copy.
__global__ void prep(const float* __restrict__ tf, const float* __restrict__ tb,
                     const float* __restrict__ pT,
                     float* __restrict__ wsf, unsigned short* __restrict__ tb_bf,
                     float* __restrict__ pT_pad) {
    if (blockIdx.x < 182) {
        int i = blockIdx.x * 256 + threadIdx.x;     // 182*256 == 208*224 exactly
        int r = i / TBK, k = i % TBK;
        const float tau = 0.5f / 196.0f;
        float v = (r < TT && k < HW) ? tb[r * HW + k] * tau : 0.0f;
        tb_bf[i] = f2bf(v);
    } else {
        if (threadIdx.x < TROWS)
            pT_pad[threadIdx.x] = (threadIdx.x < TT) ? pT[threadIdx.x] : 0.0f;
        __shared__ float red[256];
        float m = -1e30f;
        for (int i = threadIdx.x; i < HW * HW; i += 256) m = fmaxf(m, tf[i]);
        red[threadIdx.x] = m;
        __syncthreads();
        for (int s = 128; s > 0; s >>= 1) {
            if (threadIdx.x < s) red[threadIdx.x] = fmaxf(red[threadIdx.x], red[threadIdx.x + s]);
            __syncthreads();
        }
        if (threadIdx.x == 0) wsf[0] = red[0];
    }
}

// ---- k_stream: pure streaming, minimal registers, max occupancy.
// Thread-quad per (b,c) row; interleaved chunks q+4j (64B per quad per instr).
// Pass 1: running argmax, nothing retained. Pass 2: re-read x (cache-hot) +
// sel -> mask math -> coalesced stores. No LDS, no barriers.
extern "C" __global__ __launch_bounds__(256, 8)
void k_stream(const float* __restrict__ x, const float* __restrict__ tf,
              const float* __restrict__ wsf,
              float* __restrict__ xm_out, float* __restrict__ mask_out)
{
    const int tid = threadIdx.x;
    const int row = blockIdx.x * 64 + (tid >> 2);   // row = b*512 + c
    const int q   = tid & 3;
    const int nch = (q == 0) ? 13 : 12;             // q=0 also takes chunk 48
    const float rg = 1.0f / wsf[0];

    const size_t rowoff = (size_t)row * HW;
    const float* xrow = x + rowoff;

    // ---- pass 1: streaming argmax, no retention
    float bv = -__builtin_inff(); int bi = 0;
    #pragma unroll
    for (int j = 0; j < 13; ++j) if (j < nch) {
        const int k0 = (q + 4 * j) * 4;
        f32x4 xv = *(const f32x4*)(xrow + k0);
        #pragma unroll
        for (int e = 0; e < 4; ++e) {
            float v = xv[e];
            if (v > bv) { bv = v; bi = k0 + e; }    // k ascends per lane -> first kept
        }
    }
    #pragma unroll
    for (int m = 1; m <= 2; m <<= 1) {
        float ov = __shfl_xor(bv, m, 64);
        int   oi = __shfl_xor(bi, m, 64);
        if (ov > bv || (ov == bv && oi < bi)) { bv = ov; bi = oi; }
    }

    // ---- pass 2: sel + x re-read (L1/L2-hot), mask, stores
    const float* selrow = tf + (size_t)bi * HW;
    float* xmrow = xm_out + rowoff;
    float* mkrow = mask_out + rowoff;

    #pragma unroll
    for (int j = 0; j < 13; ++j) if (j < nch) {
        const int k0 = (q + 4 * j) * 4;
        f32x4 sel = *(const f32x4*)(selrow + k0);
        f32x4 xv  = *(const f32x4*)(xrow + k0);
        f32x4 mk, xm;
        #pragma unroll
        for (int e = 0; e < 4; ++e) {
            float m = fmaxf(sel[e] * rg - 0.2f, 0.0f) * 5.0f;
            mk[e] = m;
            xm[e] = xv[e] * m;
        }
        *(f32x4*)(xmrow + k0) = xm;
        *(f32x4*)(mkrow + k0) = mk;
    }
}

// ---- k_gemm: wg (c,g) = 64 batches of one channel, 4 waves. Lane (l15,lg)
// owns row b = g*64+w*16+l15; B-frags packed from xm fp32 (d_out, L3-hot).
// mt-outer loop -> only ONE f32x4 acc live (low regs, 20 waves/CU).
// Writes exp col-partials (colp) and, when ws allows, the tr tile in bf16.
extern "C" __global__ __launch_bounds__(256, 5)
void k_gemm(const float* __restrict__ xm, const unsigned short* __restrict__ tb_bf,
            float* __restrict__ colp, unsigned short* __restrict__ trs, int big)
{
    __shared__ float s_col[4][TROWS];
    const int tid  = threadIdx.x;
    const int lane = tid & 63;
    const int w    = tid >> 6;
    const int l15  = lane & 15, lg = lane >> 4;
    const int c    = blockIdx.x >> 2, g = blockIdx.x & 3;

    const int b = g * 64 + w * 16 + l15;
    const float* xrow = xm + ((size_t)b * CCH + c) * HW;

    // ---- B-frag pack straight from xm
    bf16x8 fr[7];
    #pragma unroll
    for (int kt = 0; kt < 6; ++kt) {
        f32x4 u0 = *(const f32x4*)(xrow + kt * 32 + lg * 8);
        f32x4 u1 = *(const f32x4*)(xrow + kt * 32 + lg * 8 + 4);
        #pragma unroll
        for (int e = 0; e < 4; ++e) {
            fr[kt][e]     = (short)f2bf(u0[e]);
            fr[kt][e + 4] = (short)f2bf(u1[e]);
        }
    }
    fr[6] = (bf16x8){0, 0, 0, 0, 0, 0, 0, 0};
    if (lg == 0) {
        f32x4 u0 = *(const f32x4*)(xrow + 192);
        #pragma unroll
        for (int e = 0; e < 4; ++e) fr[6][e] = (short)f2bf(u0[e]);
    }

    unsigned short* trow = trs + ((size_t)c * BB + b) * TROWS;

    #pragma unroll 1
    for (int mt = 0; mt < 13; ++mt) {
        const unsigned short* arow = tb_bf + (mt * 16 + l15) * TBK;
        f32x4 acc = (f32x4){0.f, 0.f, 0.f, 0.f};
        #pragma unroll
        for (int kt = 0; kt < 7; ++kt) {
            bf16x8 afrag = *(const bf16x8*)(arow + kt * 32 + lg * 8);
            acc = __builtin_amdgcn_mfma_f32_16x16x32_bf16(afrag, fr[kt], acc, 0, 0, 0);
        }
        // tr store (bf16) for the loss kernel
        if (big) {
            us4 pk;
            #pragma unroll
            for (int e = 0; e < 4; ++e) pk[e] = f2bf(acc[e]);
            *(us4*)(trow + mt * 16 + lg * 4) = pk;
        }
        // exp col-partials over this wave's 16 b (reduce over l15)
        f32x4 s;
        #pragma unroll
        for (int e = 0; e < 4; ++e) s[e] = __expf(acc[e]);
        #pragma unroll
        for (int m = 1; m <= 8; m <<= 1) {
            #pragma unroll
            for (int e = 0; e < 4; ++e) s[e] += __shfl_xor(s[e], m, 64);
        }
        if (l15 == 0) *(f32x4*)(&s_col[w][mt * 16 + lg * 4]) = s;
    }
    __syncthreads();
    if (tid < TROWS) {
        float s = s_col[0][tid] + s_col[1][tid] + s_col[2][tid] + s_col[3][tid];
        colp[(size_t)g * CST + c * TROWS + tid] = s;
    }
}

// ---- k_loss_big: wg (c,g), quad per b. Reads tr bf16 + colp -> px, loss.
extern "C" __global__ __launch_bounds__(256, 8)
void k_loss_big(const unsigned short* __restrict__ trs, const float* __restrict__ pT_pad,
                const float* __restrict__ colp, float* __restrict__ loss_part)
{
    __shared__ float rAs[TROWS];
    __shared__ float pTs[TROWS];
    __shared__ float red[4];

    const int tid  = threadIdx.x;
    const int lane = tid & 63;
    const int w    = tid >> 6;
    const int c    = blockIdx.x >> 2, g = blockIdx.x & 3;

    if (tid < TROWS) {
        const float* cpc = colp + (size_t)c * TROWS + tid;
        rAs[tid] = 1.0f / (cpc[0] + cpc[CST] + cpc[2 * CST] + cpc[3 * CST]);
        pTs[tid] = pT_pad[tid];
    }
    __syncthreads();

    const int p = tid & 3;
    const int b = g * 64 + (tid >> 2);
    const unsigned short* trow = trs + ((size_t)c * BB + b) * TROWS;

    float px = 0.f;
    #pragma unroll
    for (int j = 0; j < 13; ++j) {
        const int t0 = (p + 4 * j) * 4;
        us4 tv = *(const us4*)(trow + t0);
        #pragma unroll
        for (int e = 0; e < 4; ++e)
            px += pTs[t0 + e] * __expf(bf2f(tv[e])) * rAs[t0 + e];
    }
    px += __shfl_xor(px, 1, 64);
    px += __shfl_xor(px, 2, 64);
    const float rpx = 1.0f / px;

    float part = 0.f;
    #pragma unroll
    for (int j = 0; j < 13; ++j) {
        const int t0 = (p + 4 * j) * 4;
        us4 tv = *(const us4*)(trow + t0);
        #pragma unroll
        for (int e = 0; e < 4; ++e) {
            float pv = __expf(bf2f(tv[e])) * rAs[t0 + e];
            part += pTs[t0 + e] * pv * __logf(pv * rpx);
        }
    }
    #pragma unroll
    for (int off = 1; off <= 32; off <<= 1) part += __shfl_xor(part, off, 64);
    if (lane == 0) red[w] = part;
    __syncthreads();
    if (tid == 0) loss_part[(size_t)c * 4 + g] = red[0] + red[1] + red[2] + red[3];
}

// ---- k_loss_fb: fallback when ws is too small — recompute GEMM from xm
// (round-6 k2_loss, known-correct).
extern "C" __global__ __launch_bounds__(256, 4)
void k_loss_fb(const float* __restrict__ xm, const unsigned short* __restrict__ tb_bf,
               const float* __restrict__ pT_pad, const float* __restrict__ colp,
               float* __restrict__ loss_part)
{
    __shared__ float red[4];
    const int tid  = threadIdx.x;
    const int lane = tid & 63;
    const int w    = tid >> 6;
    const int l15  = lane & 15, lg = lane >> 4;
    const int c    = blockIdx.x >> 2, g = blockIdx.x & 3;

    const int b = g * 64 + w * 16 + l15;
    const float* xrow = xm + ((size_t)b * CCH + c) * HW;

    bf16x8 fr[7];
    #pragma unroll
    for (int kt = 0; kt < 6; ++kt) {
        f32x4 u0 = *(const f32x4*)(xrow + kt * 32 + lg * 8);
        f32x4 u1 = *(const f32x4*)(xrow + kt * 32 + lg * 8 + 4);
        #pragma unroll
        for (int e = 0; e < 4; ++e) {
            fr[kt][e]     = (short)f2bf(u0[e]);
            fr[kt][e + 4] = (short)f2bf(u1[e]);
        }
    }
    fr[6] = (bf16x8){0, 0, 0, 0, 0, 0, 0, 0};
    if (lg == 0) {
        f32x4 u0 = *(const f32x4*)(xrow + 192);
        #pragma unroll
        for (int e = 0; e < 4; ++e) fr[6][e] = (short)f2bf(u0[e]);
    }

    f32x4 acc[13];
    #pragma unroll
    for (int mt = 0; mt < 13; ++mt) acc[mt] = (f32x4){0.f, 0.f, 0.f, 0.f};
    #pragma unroll
    for (int kt = 0; kt < 7; ++kt) {
        const int kb = kt * 32 + lg * 8;
        const bf16x8 bfrag = fr[kt];
        #pragma unroll
        for (int mt = 0; mt < 13; ++mt) {
            bf16x8 afrag = *(const bf16x8*)(tb_bf + (mt * 16 + l15) * TBK + kb);
            acc[mt] = __builtin_amdgcn_mfma_f32_16x16x32_bf16(afrag, bfrag, acc[mt], 0, 0, 0);
        }
    }

    const float* cpc = colp + (size_t)c * TROWS;
    float px = 0.f;
    #pragma unroll
    for (int mt = 0; mt < 13; ++mt) {
        const int t0 = mt * 16 + lg * 4;
        f32x4 a0 = *(const f32x4*)(cpc + 0 * CST + t0);
        f32x4 a1 = *(const f32x4*)(cpc + 1 * CST + t0);
        f32x4 a2 = *(const f32x4*)(cpc + 2 * CST + t0);
        f32x4 a3 = *(const f32x4*)(cpc + 3 * CST + t0);
        f32x4 pt = *(const f32x4*)(pT_pad + t0);
        #pragma unroll
        for (int e = 0; e < 4; ++e) {
            float p = __expf(acc[mt][e]) / (a0[e] + a1[e] + a2[e] + a3[e]);
            acc[mt][e] = p;
            px += pt[e] * p;
        }
    }
    px += __shfl_xor(px, 16, 64);
    px += __shfl_xor(px, 32, 64);
    const float rpx = 1.0f / px;

    float part = 0.f;
    #pragma unroll
    for (int mt = 0; mt < 13; ++mt) {
        const int t0 = mt * 16 + lg * 4;
        f32x4 pt = *(const f32x4*)(pT_pad + t0);
        #pragma unroll
        for (int e = 0; e < 4; ++e)
            part += pt[e] * acc[mt][e] * __logf(acc[mt][e] * rpx);
    }
    #pragma unroll
    for (int off = 1; off <= 32; off <<= 1) part += __shfl_xor(part, off, 64);
    if (lane == 0) red[w] = part;
    __syncthreads();
    if (tid == 0) loss_part[(size_t)c * 4 + g] = red[0] + red[1] + red[2] + red[3];
}

// ---- k_fin: fold 4 wg-partials per channel
__global__ void k_fin(const float* __restrict__ lp, float* __restrict__ loss_out) {
    int c = blockIdx.x * 256 + threadIdx.x;
    if (c < CCH)
        loss_out[c] = -(lp[4 * c] + lp[4 * c + 1] + lp[4 * c + 2] + lp[4 * c + 3]);
}

extern "C" void kernel_launch(void* const* d_in, const int* in_sizes, int n_in,
                              void* d_out, int out_size, void* d_ws, size_t ws_size,
                              hipStream_t stream) {
    const float* x  = (const float*)d_in[0];
    const float* tf = (const float*)d_in[1];
    const float* tb = (const float*)d_in[2];
    const float* pT = (const float*)d_in[3];

    const size_t NOUT = (size_t)BB * CCH * HW;
    float* xm_out = (float*)d_out;
    float* mk_out = xm_out + NOUT;
    float* ls_out = mk_out + NOUT;

    // ws layout: wsf | tb_bf | pT_pad | colp | lpart | trs (bf16, big path)
    char* wsp = (char*)d_ws;
    float*          wsf    = (float*)wsp;                         // 4 B
    unsigned short* tb_bf  = (unsigned short*)(wsp + 64);         // 93184 B
    float*          pT_pad = (float*)(wsp + 93248);               // 832 B
    float*          colp   = (float*)(wsp + 94080);               // 1703936 B
    float*          lpart  = (float*)(wsp + 1798016);             // 8192 B
    unsigned short* trs    = (unsigned short*)(wsp + 1806208);    // 54525952 B

    const int big = (ws_size >= (size_t)1806208 + 54525952) ? 1 : 0;

    prep<<<183, 256, 0, stream>>>(tf, tb, pT, wsf, tb_bf, pT_pad);
    k_stream<<<2048, 256, 0, stream>>>(x, tf, wsf, xm_out, mk_out);
    k_gemm<<<2048, 256, 0, stream>>>(xm_out, tb_bf, colp, big ? trs : (unsigned short*)colp, big);
    if (big) k_loss_big<<<2048, 256, 0, stream>>>(trs, pT_pad, colp, lpart);
    else     k_loss_fb<<<2048, 256, 0, stream>>>(xm_out, tb_bf, pT_pad, colp, lpart);
    k_fin<<<2, 256, 0, stream>>>(lpart, ls_out);
}

// Round 8
// 186.859 us; speedup vs baseline: 1.7391x; 1.7391x over previous
//
#include <hip/hip_runtime.h>

// Problem constants
#define BB 256      // batch
#define CCH 512     // channels
#define HW 196      // 14*14 spatial
#define TT 197      // templates_b rows (196 + 1 negative)
#define TROWS 208   // padded T rows (13 * 16)
#define TBK 224     // padded K for templates (7 * 32)

typedef __attribute__((ext_vector_type(8))) short bf16x8;
typedef __attribute__((ext_vector_type(4))) float f32x4;

__device__ __forceinline__ unsigned short f2bf(float f) {
    union { float f; unsigned u; } v; v.f = f;
    unsigned r = v.u + 0x7FFFu + ((v.u >> 16) & 1u);   // round-to-nearest-even
    return (unsigned short)(r >> 16);
}

// ---- prep: wgs 0..181 convert templates_b*tau -> bf16 zero-padded 208x224;
// wg 182 computes gmax = max(templates_f) (the base's center peak is inside
// every 14x14 window, so max(sel) == max(templates_f) for any selection).
__global__ void prep(const float* __restrict__ tf, const float* __restrict__ tb,
                     float* __restrict__ wsf, unsigned short* __restrict__ tb_bf) {
    if (blockIdx.x < 182) {
        int i = blockIdx.x * 256 + threadIdx.x;     // 182*256 == 208*224 exactly
        int r = i / TBK, k = i % TBK;
        const float tau = 0.5f / 196.0f;
        float v = (r < TT && k < HW) ? tb[r * HW + k] * tau : 0.0f;
        tb_bf[i] = f2bf(v);
    } else {
        __shared__ float red[256];
        float m = -1e30f;
        for (int i = threadIdx.x; i < HW * HW; i += 256) m = fmaxf(m, tf[i]);
        red[threadIdx.x] = m;
        __syncthreads();
        for (int s = 128; s > 0; s >>= 1) {
            if (threadIdx.x < s) red[threadIdx.x] = fmaxf(red[threadIdx.x], red[threadIdx.x + s]);
            __syncthreads();
        }
        if (threadIdx.x == 0) wsf[0] = red[0];
    }
}

// ---- fused kernel: one wg (1024 thr, 16 waves) per channel, NO LDS data tile.
// Wave w stages its own 16 batch rows straight into B-fragment registers:
// lane (l15,lg) owns row b=w*16+l15, chunks kt*8+2*lg+{0,1} (k = kt*32+lg*8..+7)
// == exactly the mfma_16x16x32 B-frag layout. No stage->GEMM barrier; only the
// two softmax reductions synchronize waves.
// __launch_bounds__(1024, 4): 4 waves/EU min = exactly 1 wg/CU -> 128-VGPR cap.
// The kernel needs ~100 live VGPRs (u[13]+fr[7]+acc[13]); at 64 it spilled.
extern "C" __global__ __launch_bounds__(1024, 4)
void fused_one(const float* __restrict__ x, const float* __restrict__ tf,
               const float* __restrict__ pT, const unsigned short* __restrict__ tb_bf,
               const float* __restrict__ wsf,
               float* __restrict__ xm_out, float* __restrict__ mask_out,
               float* __restrict__ loss_out)
{
    __shared__ float s_part[16 * TROWS];
    __shared__ float rAs[TROWS];
    __shared__ float pTs[TROWS];
    __shared__ float red[16];

    const int c    = blockIdx.x;
    const int tid  = threadIdx.x;
    const int lane = tid & 63;
    const int w    = tid >> 6;
    const int l15  = lane & 15, lg = lane >> 4;
    const float rg = 1.0f / wsf[0];

    if (tid < TROWS) pTs[tid] = (tid < TT) ? pT[tid] : 0.0f;

    const int b = w * 16 + l15;
    const size_t rowoff = ((size_t)b * CCH + c) * HW;
    const float* xrow = x + rowoff;

    // ---- load this lane's 12 (13 for lg==0) chunks of its row
    f32x4 u[13];
    #pragma unroll
    for (int kt = 0; kt < 6; ++kt) {
        u[2 * kt]     = *(const f32x4*)(xrow + kt * 32 + lg * 8);
        u[2 * kt + 1] = *(const f32x4*)(xrow + kt * 32 + lg * 8 + 4);
    }
    if (lg == 0) u[12] = *(const f32x4*)(xrow + 192);
    else         u[12] = (f32x4){-__builtin_inff(), -__builtin_inff(),
                                 -__builtin_inff(), -__builtin_inff()};

    // ---- argmax (k ascends within each lane's scan -> strict > keeps first)
    float bv = -__builtin_inff(); int bi = 0;
    #pragma unroll
    for (int j = 0; j < 13; ++j) {
        const int k0 = (j < 12) ? (((j >> 1) * 8 + lg * 2 + (j & 1)) * 4) : 192;
        #pragma unroll
        for (int e = 0; e < 4; ++e) {
            float v = u[j][e];
            if (v > bv) { bv = v; bi = k0 + e; }
        }
    }
    #pragma unroll
    for (int m = 16; m <= 32; m <<= 1) {   // reduce over lg (lanes l15+16g)
        float ov = __shfl_xor(bv, m, 64);
        int   oi = __shfl_xor(bi, m, 64);
        if (ov > bv || (ov == bv && oi < bi)) { bv = ov; bi = oi; }
    }

    // ---- mask, outputs, and B-frag pack (u dies into fr)
    const float* selrow = tf + (size_t)bi * HW;
    float* xmrow = xm_out + rowoff;
    float* mkrow = mask_out + rowoff;
    bf16x8 fr[7];

    #pragma unroll
    for (int kt = 0; kt < 6; ++kt) {
        #pragma unroll
        for (int h = 0; h < 2; ++h) {
            const int k0 = kt * 32 + lg * 8 + h * 4;
            f32x4 sel = *(const f32x4*)(selrow + k0);
            f32x4 mk, xm;
            #pragma unroll
            for (int e = 0; e < 4; ++e) {
                float m = fmaxf(sel[e] * rg - 0.2f, 0.0f) * 5.0f;
                mk[e] = m;
                xm[e] = u[2 * kt + h][e] * m;
            }
            *(f32x4*)(xmrow + k0) = xm;
            *(f32x4*)(mkrow + k0) = mk;
            #pragma unroll
            for (int e = 0; e < 4; ++e) fr[kt][h * 4 + e] = (short)f2bf(xm[e]);
        }
    }
    {   // kt=6: only lg==0 has real data (floats 192..195); rest zero-pad
        fr[6] = (bf16x8){0, 0, 0, 0, 0, 0, 0, 0};
        if (lg == 0) {
            f32x4 sel = *(const f32x4*)(selrow + 192);
            f32x4 mk, xm;
            #pragma unroll
            for (int e = 0; e < 4; ++e) {
                float m = fmaxf(sel[e] * rg - 0.2f, 0.0f) * 5.0f;
                mk[e] = m;
                xm[e] = u[12][e] * m;
            }
            *(f32x4*)(xmrow + 192) = xm;
            *(f32x4*)(mkrow + 192) = mk;
            #pragma unroll
            for (int e = 0; e < 4; ++e) fr[6][e] = (short)f2bf(xm[e]);
        }
    }

    // ---- GEMM: tr[t = mt*16+lg*4+e][b = w*16+l15], A-frags streamed from L2
    f32x4 acc[13];
    #pragma unroll
    for (int mt = 0; mt < 13; ++mt) acc[mt] = (f32x4){0.f, 0.f, 0.f, 0.f};

    #pragma unroll
    for (int kt = 0; kt < 7; ++kt) {
        const int kb = kt * 32 + lg * 8;
        const bf16x8 bfrag = fr[kt];
        #pragma unroll
        for (int mt = 0; mt < 13; ++mt) {
            bf16x8 afrag = *(const bf16x8*)(tb_bf + (mt * 16 + l15) * TBK + kb);
            acc[mt] = __builtin_amdgcn_mfma_f32_16x16x32_bf16(afrag, bfrag, acc[mt], 0, 0, 0);
        }
    }

    // ---- Phase A: exp in-register, col-sum over this wave's 16 b, cross-wave via LDS
    float* sp = s_part + w * TROWS;
    #pragma unroll
    for (int mt = 0; mt < 13; ++mt) {
        #pragma unroll
        for (int e = 0; e < 4; ++e) acc[mt][e] = __expf(acc[mt][e]);
        f32x4 s = acc[mt];
        #pragma unroll
        for (int m = 1; m <= 8; m <<= 1) {
            #pragma unroll
            for (int e = 0; e < 4; ++e) s[e] += __shfl_xor(s[e], m, 64);
        }
        if (l15 == 0) *(f32x4*)(sp + mt * 16 + lg * 4) = s;
    }
    __syncthreads();
    if (tid < TROWS) {
        float s = 0.f;
        #pragma unroll
        for (int w2 = 0; w2 < 16; ++w2) s += s_part[w2 * TROWS + tid];
        rAs[tid] = 1.0f / s;
    }
    __syncthreads();

    // ---- Phase B: p = exp*rA, px[b] = sum_t pT*p
    float px = 0.f;
    #pragma unroll
    for (int mt = 0; mt < 13; ++mt) {
        const int t0 = mt * 16 + lg * 4;
        f32x4 ra = *(const f32x4*)(rAs + t0);
        f32x4 pt = *(const f32x4*)(pTs + t0);
        #pragma unroll
        for (int e = 0; e < 4; ++e) {
            float p = acc[mt][e] * ra[e];
            acc[mt][e] = p;
            px += pt[e] * p;
        }
    }
    px += __shfl_xor(px, 16, 64);
    px += __shfl_xor(px, 32, 64);
    const float rpx = 1.0f / px;

    // ---- Phase C: loss partial = sum_t pT * p * log(p/px)
    float part = 0.f;
    #pragma unroll
    for (int mt = 0; mt < 13; ++mt) {
        const int t0 = mt * 16 + lg * 4;
        f32x4 pt = *(const f32x4*)(pTs + t0);
        #pragma unroll
        for (int e = 0; e < 4; ++e) {
            float p = acc[mt][e];
            part += pt[e] * p * __logf(p * rpx);
        }
    }
    #pragma unroll
    for (int off = 32; off >= 1; off >>= 1) part += __shfl_xor(part, off, 64);
    if (lane == 0) red[w] = part;
    __syncthreads();
    if (tid == 0) {
        float s = 0.f;
        #pragma unroll
        for (int w2 = 0; w2 < 16; ++w2) s += red[w2];
        loss_out[c] = -s;
    }
}

extern "C" void kernel_launch(void* const* d_in, const int* in_sizes, int n_in,
                              void* d_out, int out_size, void* d_ws, size_t ws_size,
                              hipStream_t stream) {
    const float* x  = (const float*)d_in[0];
    const float* tf = (const float*)d_in[1];
    const float* tb = (const float*)d_in[2];
    const float* pT = (const float*)d_in[3];

    const size_t NOUT = (size_t)BB * CCH * HW;
    float* xm_out = (float*)d_out;
    float* mk_out = xm_out + NOUT;
    float* ls_out = mk_out + NOUT;

    float* wsf = (float*)d_ws;
    unsigned short* tb_bf = (unsigned short*)((char*)d_ws + 64);   // 208*224*2 = 93184 B

    prep<<<183, 256, 0, stream>>>(tf, tb, wsf, tb_bf);
    fused_one<<<CCH, 1024, 0, stream>>>(x, tf, pT, tb_bf, wsf, xm_out, mk_out, ls_out);
}

// Round 9
// 151.246 us; speedup vs baseline: 2.1485x; 1.2355x over previous
//
#include <hip/hip_runtime.h>

// Problem constants
#define BB 256      // batch
#define CCH 512     // channels
#define HW 196      // 14*14 spatial
#define TT 197      // templates_b rows (196 + 1 negative)
#define TROWS 208   // padded T rows (13 * 16)
#define APAD 232    // A-table padded row length in shorts (464B = 29*16B rows;
                    // LDS dword stride 116 -> 8 banks x 2-way (free) for b128 reads)
#define ANUM (TROWS * APAD)   // 48256 shorts = 96512 B

typedef __attribute__((ext_vector_type(8))) short bf16x8;
typedef __attribute__((ext_vector_type(4))) float f32x4;

__device__ __forceinline__ unsigned short f2bf(float f) {
    union { float f; unsigned u; } v; v.f = f;
    unsigned r = v.u + 0x7FFFu + ((v.u >> 16) & 1u);   // round-to-nearest-even
    return (unsigned short)(r >> 16);
}

// ---- prep: wgs 0..188 convert templates_b*tau -> bf16 zero-padded 208x232;
// wg 189 computes gmax = max(templates_f) (the base's center peak is inside
// every 14x14 window, so max(sel) == max(templates_f) for any selection).
__global__ void prep(const float* __restrict__ tf, const float* __restrict__ tb,
                     float* __restrict__ wsf, unsigned short* __restrict__ tb_bf) {
    if (blockIdx.x < 189) {
        int i = blockIdx.x * 256 + threadIdx.x;
        if (i < ANUM) {
            int r = i / APAD, k = i % APAD;
            const float tau = 0.5f / 196.0f;
            float v = (r < TT && k < HW) ? tb[r * HW + k] * tau : 0.0f;
            tb_bf[i] = f2bf(v);
        }
    } else {
        __shared__ float red[256];
        float m = -1e30f;
        for (int i = threadIdx.x; i < HW * HW; i += 256) m = fmaxf(m, tf[i]);
        red[threadIdx.x] = m;
        __syncthreads();
        for (int s = 128; s > 0; s >>= 1) {
            if (threadIdx.x < s) red[threadIdx.x] = fmaxf(red[threadIdx.x], red[threadIdx.x + s]);
            __syncthreads();
        }
        if (threadIdx.x == 0) wsf[0] = red[0];
    }
}

// ---- fused kernel: one wg (1024 thr, 16 waves) per channel.
// Same structure as round 8 (register-staged B-frags, in-register softmax),
// plus: the 96.5KB A-table is copied ONCE into LDS at kernel start, so the
// 91 A-frag reads per lane come from LDS (ds_read_b128, ~2-way bank alias)
// instead of thrashing the 32KB L1 / round-tripping to L2.
extern "C" __global__ __launch_bounds__(1024, 4)
void fused_one(const float* __restrict__ x, const float* __restrict__ tf,
               const float* __restrict__ pT, const unsigned short* __restrict__ tb_bf,
               const float* __restrict__ wsf,
               float* __restrict__ xm_out, float* __restrict__ mask_out,
               float* __restrict__ loss_out)
{
    extern __shared__ char smem[];
    unsigned short* Alds = (unsigned short*)smem;                 // [208][232] bf16
    float* s_part = (float*)(smem + ANUM * 2);                    // [16][208]
    float* rAs    = s_part + 16 * TROWS;                          // [208]
    float* pTs    = rAs + TROWS;                                  // [208]
    float* red    = pTs + TROWS;                                  // [16]

    const int c    = blockIdx.x;
    const int tid  = threadIdx.x;
    const int lane = tid & 63;
    const int w    = tid >> 6;
    const int l15  = lane & 15, lg = lane >> 4;
    const float rg = 1.0f / wsf[0];

    // ---- stage A-table into LDS (6032 x 16B chunks over 1024 threads)
    {
        const f32x4* src = (const f32x4*)tb_bf;
        f32x4* dst = (f32x4*)Alds;
        #pragma unroll
        for (int it = 0; it < 6; ++it) {
            int idx = tid + it * 1024;
            if (idx < ANUM / 8) dst[idx] = src[idx];
        }
    }
    if (tid < TROWS) pTs[tid] = (tid < TT) ? pT[tid] : 0.0f;

    const int b = w * 16 + l15;
    const size_t rowoff = ((size_t)b * CCH + c) * HW;
    const float* xrow = x + rowoff;

    // ---- load this lane's 12 (13 for lg==0) chunks of its row
    f32x4 u[13];
    #pragma unroll
    for (int kt = 0; kt < 6; ++kt) {
        u[2 * kt]     = *(const f32x4*)(xrow + kt * 32 + lg * 8);
        u[2 * kt + 1] = *(const f32x4*)(xrow + kt * 32 + lg * 8 + 4);
    }
    if (lg == 0) u[12] = *(const f32x4*)(xrow + 192);
    else         u[12] = (f32x4){-__builtin_inff(), -__builtin_inff(),
                                 -__builtin_inff(), -__builtin_inff()};

    // ---- argmax (k ascends within each lane's scan -> strict > keeps first)
    float bv = -__builtin_inff(); int bi = 0;
    #pragma unroll
    for (int j = 0; j < 13; ++j) {
        const int k0 = (j < 12) ? (((j >> 1) * 8 + lg * 2 + (j & 1)) * 4) : 192;
        #pragma unroll
        for (int e = 0; e < 4; ++e) {
            float v = u[j][e];
            if (v > bv) { bv = v; bi = k0 + e; }
        }
    }
    #pragma unroll
    for (int m = 16; m <= 32; m <<= 1) {   // reduce over lg (lanes l15+16g)
        float ov = __shfl_xor(bv, m, 64);
        int   oi = __shfl_xor(bi, m, 64);
        if (ov > bv || (ov == bv && oi < bi)) { bv = ov; bi = oi; }
    }

    // ---- mask, outputs, and B-frag pack (u dies into fr)
    const float* selrow = tf + (size_t)bi * HW;
    float* xmrow = xm_out + rowoff;
    float* mkrow = mask_out + rowoff;
    bf16x8 fr[7];

    #pragma unroll
    for (int kt = 0; kt < 6; ++kt) {
        #pragma unroll
        for (int h = 0; h < 2; ++h) {
            const int k0 = kt * 32 + lg * 8 + h * 4;
            f32x4 sel = *(const f32x4*)(selrow + k0);
            f32x4 mk, xm;
            #pragma unroll
            for (int e = 0; e < 4; ++e) {
                float m = fmaxf(sel[e] * rg - 0.2f, 0.0f) * 5.0f;
                mk[e] = m;
                xm[e] = u[2 * kt + h][e] * m;
            }
            *(f32x4*)(xmrow + k0) = xm;
            *(f32x4*)(mkrow + k0) = mk;
            #pragma unroll
            for (int e = 0; e < 4; ++e) fr[kt][h * 4 + e] = (short)f2bf(xm[e]);
        }
    }
    {   // kt=6: only lg==0 has real data (floats 192..195); rest zero-pad
        fr[6] = (bf16x8){0, 0, 0, 0, 0, 0, 0, 0};
        if (lg == 0) {
            f32x4 sel = *(const f32x4*)(selrow + 192);
            f32x4 mk, xm;
            #pragma unroll
            for (int e = 0; e < 4; ++e) {
                float m = fmaxf(sel[e] * rg - 0.2f, 0.0f) * 5.0f;
                mk[e] = m;
                xm[e] = u[12][e] * m;
            }
            *(f32x4*)(xmrow + 192) = xm;
            *(f32x4*)(mkrow + 192) = mk;
            #pragma unroll
            for (int e = 0; e < 4; ++e) fr[6][e] = (short)f2bf(xm[e]);
        }
    }

    __syncthreads();   // A-table staged (long ago) -> visible to all waves

    // ---- GEMM: tr[t = mt*16+lg*4+e][b = w*16+l15], A-frags from LDS
    f32x4 acc[13];
    #pragma unroll
    for (int mt = 0; mt < 13; ++mt) acc[mt] = (f32x4){0.f, 0.f, 0.f, 0.f};

    #pragma unroll
    for (int kt = 0; kt < 7; ++kt) {
        const int kb = kt * 32 + lg * 8;
        const bf16x8 bfrag = fr[kt];
        #pragma unroll
        for (int mt = 0; mt < 13; ++mt) {
            bf16x8 afrag = *(const bf16x8*)(Alds + (mt * 16 + l15) * APAD + kb);
            acc[mt] = __builtin_amdgcn_mfma_f32_16x16x32_bf16(afrag, bfrag, acc[mt], 0, 0, 0);
        }
    }

    // ---- Phase A: exp in-register, col-sum over this wave's 16 b, cross-wave via LDS
    float* sp = s_part + w * TROWS;
    #pragma unroll
    for (int mt = 0; mt < 13; ++mt) {
        #pragma unroll
        for (int e = 0; e < 4; ++e) acc[mt][e] = __expf(acc[mt][e]);
        f32x4 s = acc[mt];
        #pragma unroll
        for (int m = 1; m <= 8; m <<= 1) {
            #pragma unroll
            for (int e = 0; e < 4; ++e) s[e] += __shfl_xor(s[e], m, 64);
        }
        if (l15 == 0) *(f32x4*)(sp + mt * 16 + lg * 4) = s;
    }
    __syncthreads();
    if (tid < TROWS) {
        float s = 0.f;
        #pragma unroll
        for (int w2 = 0; w2 < 16; ++w2) s += s_part[w2 * TROWS + tid];
        rAs[tid] = 1.0f / s;
    }
    __syncthreads();

    // ---- Phase B: p = exp*rA, px[b] = sum_t pT*p
    float px = 0.f;
    #pragma unroll
    for (int mt = 0; mt < 13; ++mt) {
        const int t0 = mt * 16 + lg * 4;
        f32x4 ra = *(const f32x4*)(rAs + t0);
        f32x4 pt = *(const f32x4*)(pTs + t0);
        #pragma unroll
        for (int e = 0; e < 4; ++e) {
            float p = acc[mt][e] * ra[e];
            acc[mt][e] = p;
            px += pt[e] * p;
        }
    }
    px += __shfl_xor(px, 16, 64);
    px += __shfl_xor(px, 32, 64);
    const float rpx = 1.0f / px;

    // ---- Phase C: loss partial = sum_t pT * p * log(p/px)
    float part = 0.f;
    #pragma unroll
    for (int mt = 0; mt < 13; ++mt) {
        const int t0 = mt * 16 + lg * 4;
        f32x4 pt = *(const f32x4*)(pTs + t0);
        #pragma unroll
        for (int e = 0; e < 4; ++e) {
            float p = acc[mt][e];
            part += pt[e] * p * __logf(p * rpx);
        }
    }
    #pragma unroll
    for (int off = 32; off >= 1; off >>= 1) part += __shfl_xor(part, off, 64);
    if (lane == 0) red[w] = part;
    __syncthreads();
    if (tid == 0) {
        float s = 0.f;
        #pragma unroll
        for (int w2 = 0; w2 < 16; ++w2) s += red[w2];
        loss_out[c] = -s;
    }
}

extern "C" void kernel_launch(void* const* d_in, const int* in_sizes, int n_in,
                              void* d_out, int out_size, void* d_ws, size_t ws_size,
                              hipStream_t stream) {
    const float* x  = (const float*)d_in[0];
    const float* tf = (const float*)d_in[1];
    const float* tb = (const float*)d_in[2];
    const float* pT = (const float*)d_in[3];

    const size_t NOUT = (size_t)BB * CCH * HW;
    float* xm_out = (float*)d_out;
    float* mk_out = xm_out + NOUT;
    float* ls_out = mk_out + NOUT;

    float* wsf = (float*)d_ws;
    unsigned short* tb_bf = (unsigned short*)((char*)d_ws + 64);   // 208*232*2 = 96512 B

    prep<<<190, 256, 0, stream>>>(tf, tb, wsf, tb_bf);

    const size_t SMEM = (size_t)ANUM * 2                 // A-table: 96512
                      + 16 * TROWS * 4                   // s_part: 13312
                      + TROWS * 4 + TROWS * 4 + 16 * 4;  // rAs + pTs + red
    hipFuncSetAttribute((const void*)fused_one, hipFuncAttributeMaxDynamicSharedMemorySize, (int)SMEM);
    fused_one<<<dim3(CCH), dim3(1024), SMEM, stream>>>(x, tf, pT, tb_bf, wsf,
                                                       xm_out, mk_out, ls_out);
}

// Round 10
// 146.122 us; speedup vs baseline: 2.2239x; 1.0351x over previous
//
#include <hip/hip_runtime.h>

// Problem constants
#define BB 256      // batch
#define CCH 512     // channels
#define HW 196      // 14*14 spatial
#define TT 197      // templates_b rows (196 + 1 negative)
#define TROWS 208   // padded T rows (13 * 16)
#define NFRAG (13 * 7)            // (mt, kt) fragment blocks
#define ASHORTS (NFRAG * 64 * 8)  // 46592 shorts = 93184 B

typedef __attribute__((ext_vector_type(8))) short bf16x8;
typedef __attribute__((ext_vector_type(4))) float f32x4;

__device__ __forceinline__ unsigned short f2bf(float f) {
    union { float f; unsigned u; } v; v.f = f;
    unsigned r = v.u + 0x7FFFu + ((v.u >> 16) & 1u);   // round-to-nearest-even
    return (unsigned short)(r >> 16);
}

// ---- prep: wgs 0..181 build the A-table in FRAGMENT-CONTIGUOUS order:
// A[mt][kt][lane][j] = templates_b[mt*16 + (lane&15)][kt*32 + (lane>>4)*8 + j] * tau
// so each MFMA A-operand (one (mt,kt) block) is 1024 contiguous bytes in LDS.
// wg 182 computes gmax = max(templates_f) (the base's center peak is inside
// every 14x14 window, so max(sel) == max(templates_f) for any selection).
__global__ void prep(const float* __restrict__ tf, const float* __restrict__ tb,
                     float* __restrict__ wsf, unsigned short* __restrict__ tb_bf) {
    if (blockIdx.x < 182) {
        int i = blockIdx.x * 256 + threadIdx.x;     // 182*256 == 46592 exactly
        int frag = i >> 9;                          // 512 shorts per (mt,kt) block
        int s    = i & 511;
        int mt = frag / 7, kt = frag % 7;
        int lane = s >> 3, j = s & 7;
        int r = mt * 16 + (lane & 15);
        int k = kt * 32 + (lane >> 4) * 8 + j;
        const float tau = 0.5f / 196.0f;
        float v = (r < TT && k < HW) ? tb[r * HW + k] * tau : 0.0f;
        tb_bf[i] = f2bf(v);
    } else {
        __shared__ float red[256];
        float m = -1e30f;
        for (int i = threadIdx.x; i < HW * HW; i += 256) m = fmaxf(m, tf[i]);
        red[threadIdx.x] = m;
        __syncthreads();
        for (int s = 128; s > 0; s >>= 1) {
            if (threadIdx.x < s) red[threadIdx.x] = fmaxf(red[threadIdx.x], red[threadIdx.x + s]);
            __syncthreads();
        }
        if (threadIdx.x == 0) wsf[0] = red[0];
    }
}

// ---- fused kernel: one wg (1024 thr, 16 waves) per channel.
// Register-staged B-frags, LDS A-table (fragment-contiguous -> conflict-free
// sequential ds_read_b128), in-register softmax/loss.
// amdgpu_waves_per_eu(4,4): LDS already caps us at 1 wg/CU = 4 waves/EU, so
// pin the scheduler there -> full 128-VGPR budget -> all 13 x-loads batch.
extern "C" __global__ __launch_bounds__(1024)
__attribute__((amdgpu_waves_per_eu(4, 4)))
void fused_one(const float* __restrict__ x, const float* __restrict__ tf,
               const float* __restrict__ pT, const unsigned short* __restrict__ tb_bf,
               const float* __restrict__ wsf,
               float* __restrict__ xm_out, float* __restrict__ mask_out,
               float* __restrict__ loss_out)
{
    extern __shared__ char smem[];
    unsigned short* Alds = (unsigned short*)smem;                 // [91][512] bf16 frags
    float* s_part = (float*)(smem + ASHORTS * 2);                 // [16][208]
    float* rAs    = s_part + 16 * TROWS;                          // [208]
    float* pTs    = rAs + TROWS;                                  // [208]
    float* red    = pTs + TROWS;                                  // [16]

    const int c    = blockIdx.x;
    const int tid  = threadIdx.x;
    const int lane = tid & 63;
    const int w    = tid >> 6;
    const int l15  = lane & 15, lg = lane >> 4;
    const float rg = 1.0f / wsf[0];

    // ---- stage A-table into LDS (5824 x 16B chunks over 1024 threads)
    {
        const f32x4* src = (const f32x4*)tb_bf;
        f32x4* dst = (f32x4*)Alds;
        #pragma unroll
        for (int it = 0; it < 6; ++it) {
            int idx = tid + it * 1024;
            if (idx < ASHORTS / 8) dst[idx] = src[idx];
        }
    }
    if (tid < TROWS) pTs[tid] = (tid < TT) ? pT[tid] : 0.0f;

    const int b = w * 16 + l15;
    const size_t rowoff = ((size_t)b * CCH + c) * HW;
    const float* xrow = x + rowoff;

    // ---- load this lane's 12 (13 for lg==0) chunks of its row
    f32x4 u[13];
    #pragma unroll
    for (int kt = 0; kt < 6; ++kt) {
        u[2 * kt]     = *(const f32x4*)(xrow + kt * 32 + lg * 8);
        u[2 * kt + 1] = *(const f32x4*)(xrow + kt * 32 + lg * 8 + 4);
    }
    if (lg == 0) u[12] = *(const f32x4*)(xrow + 192);
    else         u[12] = (f32x4){-__builtin_inff(), -__builtin_inff(),
                                 -__builtin_inff(), -__builtin_inff()};

    // ---- argmax (k ascends within each lane's scan -> strict > keeps first)
    float bv = -__builtin_inff(); int bi = 0;
    #pragma unroll
    for (int j = 0; j < 13; ++j) {
        const int k0 = (j < 12) ? (((j >> 1) * 8 + lg * 2 + (j & 1)) * 4) : 192;
        #pragma unroll
        for (int e = 0; e < 4; ++e) {
            float v = u[j][e];
            if (v > bv) { bv = v; bi = k0 + e; }
        }
    }
    #pragma unroll
    for (int m = 16; m <= 32; m <<= 1) {   // reduce over lg (lanes l15+16g)
        float ov = __shfl_xor(bv, m, 64);
        int   oi = __shfl_xor(bi, m, 64);
        if (ov > bv || (ov == bv && oi < bi)) { bv = ov; bi = oi; }
    }

    // ---- mask, outputs, and B-frag pack (u dies into fr)
    const float* selrow = tf + (size_t)bi * HW;
    float* xmrow = xm_out + rowoff;
    float* mkrow = mask_out + rowoff;
    bf16x8 fr[7];

    #pragma unroll
    for (int kt = 0; kt < 6; ++kt) {
        #pragma unroll
        for (int h = 0; h < 2; ++h) {
            const int k0 = kt * 32 + lg * 8 + h * 4;
            f32x4 sel = *(const f32x4*)(selrow + k0);
            f32x4 mk, xm;
            #pragma unroll
            for (int e = 0; e < 4; ++e) {
                float m = fmaxf(sel[e] * rg - 0.2f, 0.0f) * 5.0f;
                mk[e] = m;
                xm[e] = u[2 * kt + h][e] * m;
            }
            *(f32x4*)(xmrow + k0) = xm;
            *(f32x4*)(mkrow + k0) = mk;
            #pragma unroll
            for (int e = 0; e < 4; ++e) fr[kt][h * 4 + e] = (short)f2bf(xm[e]);
        }
    }
    {   // kt=6: only lg==0 has real data (floats 192..195); rest zero-pad
        fr[6] = (bf16x8){0, 0, 0, 0, 0, 0, 0, 0};
        if (lg == 0) {
            f32x4 sel = *(const f32x4*)(selrow + 192);
            f32x4 mk, xm;
            #pragma unroll
            for (int e = 0; e < 4; ++e) {
                float m = fmaxf(sel[e] * rg - 0.2f, 0.0f) * 5.0f;
                mk[e] = m;
                xm[e] = u[12][e] * m;
            }
            *(f32x4*)(xmrow + 192) = xm;
            *(f32x4*)(mkrow + 192) = mk;
            #pragma unroll
            for (int e = 0; e < 4; ++e) fr[6][e] = (short)f2bf(xm[e]);
        }
    }

    __syncthreads();   // A-table staged (long ago) -> visible to all waves

    // ---- GEMM: tr[t = mt*16+lg*4+e][b = w*16+l15]; A-frags are 1024B
    // CONTIGUOUS LDS blocks: addr = (mt*7+kt)*1024B + lane*16B (seq, 0-conflict)
    f32x4 acc[13];
    #pragma unroll
    for (int mt = 0; mt < 13; ++mt) acc[mt] = (f32x4){0.f, 0.f, 0.f, 0.f};

    const unsigned short* Abase = Alds + lane * 8;
    #pragma unroll
    for (int kt = 0; kt < 7; ++kt) {
        const bf16x8 bfrag = fr[kt];
        #pragma unroll
        for (int mt = 0; mt < 13; ++mt) {
            bf16x8 afrag = *(const bf16x8*)(Abase + (mt * 7 + kt) * 512);
            acc[mt] = __builtin_amdgcn_mfma_f32_16x16x32_bf16(afrag, bfrag, acc[mt], 0, 0, 0);
        }
    }

    // ---- Phase A: exp in-register, col-sum over this wave's 16 b, cross-wave via LDS
    float* sp = s_part + w * TROWS;
    #pragma unroll
    for (int mt = 0; mt < 13; ++mt) {
        #pragma unroll
        for (int e = 0; e < 4; ++e) acc[mt][e] = __expf(acc[mt][e]);
        f32x4 s = acc[mt];
        #pragma unroll
        for (int m = 1; m <= 8; m <<= 1) {
            #pragma unroll
            for (int e = 0; e < 4; ++e) s[e] += __shfl_xor(s[e], m, 64);
        }
        if (l15 == 0) *(f32x4*)(sp + mt * 16 + lg * 4) = s;
    }
    __syncthreads();
    if (tid < TROWS) {
        float s = 0.f;
        #pragma unroll
        for (int w2 = 0; w2 < 16; ++w2) s += s_part[w2 * TROWS + tid];
        rAs[tid] = 1.0f / s;
    }
    __syncthreads();

    // ---- Phase B: p = exp*rA, px[b] = sum_t pT*p
    float px = 0.f;
    #pragma unroll
    for (int mt = 0; mt < 13; ++mt) {
        const int t0 = mt * 16 + lg * 4;
        f32x4 ra = *(const f32x4*)(rAs + t0);
        f32x4 pt = *(const f32x4*)(pTs + t0);
        #pragma unroll
        for (int e = 0; e < 4; ++e) {
            float p = acc[mt][e] * ra[e];
            acc[mt][e] = p;
            px += pt[e] * p;
        }
    }
    px += __shfl_xor(px, 16, 64);
    px += __shfl_xor(px, 32, 64);
    const float rpx = 1.0f / px;

    // ---- Phase C: loss partial = sum_t pT * p * log(p/px)
    float part = 0.f;
    #pragma unroll
    for (int mt = 0; mt < 13; ++mt) {
        const int t0 = mt * 16 + lg * 4;
        f32x4 pt = *(const f32x4*)(pTs + t0);
        #pragma unroll
        for (int e = 0; e < 4; ++e) {
            float p = acc[mt][e];
            part += pt[e] * p * __logf(p * rpx);
        }
    }
    #pragma unroll
    for (int off = 32; off >= 1; off >>= 1) part += __shfl_xor(part, off, 64);
    if (lane == 0) red[w] = part;
    __syncthreads();
    if (tid == 0) {
        float s = 0.f;
        #pragma unroll
        for (int w2 = 0; w2 < 16; ++w2) s += red[w2];
        loss_out[c] = -s;
    }
}

extern "C" void kernel_launch(void* const* d_in, const int* in_sizes, int n_in,
                              void* d_out, int out_size, void* d_ws, size_t ws_size,
                              hipStream_t stream) {
    const float* x  = (const float*)d_in[0];
    const float* tf = (const float*)d_in[1];
    const float* tb = (const float*)d_in[2];
    const float* pT = (const float*)d_in[3];

    const size_t NOUT = (size_t)BB * CCH * HW;
    float* xm_out = (float*)d_out;
    float* mk_out = xm_out + NOUT;
    float* ls_out = mk_out + NOUT;

    float* wsf = (float*)d_ws;
    unsigned short* tb_bf = (unsigned short*)((char*)d_ws + 64);   // 93184 B

    prep<<<183, 256, 0, stream>>>(tf, tb, wsf, tb_bf);

    const size_t SMEM = (size_t)ASHORTS * 2              // A-table: 93184
                      + 16 * TROWS * 4                   // s_part: 13312
                      + TROWS * 4 + TROWS * 4 + 16 * 4;  // rAs + pTs + red
    hipFuncSetAttribute((const void*)fused_one, hipFuncAttributeMaxDynamicSharedMemorySize, (int)SMEM);
    fused_one<<<dim3(CCH), dim3(1024), SMEM, stream>>>(x, tf, pT, tb_bf, wsf,
                                                       xm_out, mk_out, ls_out);
}